// Round 7
// baseline (188.447 us; speedup 1.0000x reference)
//
#include <hip/hip_runtime.h>
#include <math.h>

typedef __attribute__((ext_vector_type(4))) float f32x4;
typedef __attribute__((ext_vector_type(8))) short bf16x8;

#define HH 128
#define WW 128
#define HWSZ 16384
#define BHW 131072
#define BB 8

__device__ __forceinline__ float bf2f(ushort u) {
    union { uint i; float f; } x; x.i = ((uint)u) << 16; return x.f;
}
__device__ __forceinline__ ushort f2bf(float f) {
    union { float f; uint i; } x; x.f = f;
    uint r = (x.i + 0x7fffu + ((x.i >> 16) & 1u)) >> 16;
    return (ushort)r;
}

// NCHW fp32 (C=64) -> group-planar bf16 xg[b][cg][hw][8].
__global__ __launch_bounds__(256) void to_gp_bf16(const float* __restrict__ x,
                                                  ushort* __restrict__ y) {
    __shared__ ushort lds[64][66];
    int blk = blockIdx.x;
    int b = blk >> 8;
    int hw0 = (blk & 255) << 6;
    int t = threadIdx.x;
    int lane = t & 63;
    int q = t >> 6;
#pragma unroll
    for (int i = 0; i < 16; i++) {
        int c = i * 4 + q;
        lds[c][lane] = f2bf(x[((size_t)(b * 64 + c) << 14) + hw0 + lane]);
    }
    __syncthreads();
#pragma unroll
    for (int it = 0; it < 2; it++) {
        int id = it * 256 + t;
        int cg = id >> 6;
        int px = id & 63;
        uint pk[4];
#pragma unroll
        for (int j = 0; j < 4; j++)
            pk[j] = (uint)lds[cg * 8 + 2 * j][px] | ((uint)lds[cg * 8 + 2 * j + 1][px] << 16);
        *(uint4*)(y + ((((size_t)b * 8 + cg) << 14) + hw0 + px) * 8) = *(uint4*)pk;
    }
}

// w[Co][64][3][3] fp32 -> wa[Co_pad][576] bf16 with r = kk*64+ci (zero-padded rows).
__global__ __launch_bounds__(256) void prep_wa(const float* __restrict__ w,
                                               ushort* __restrict__ wa, int Co, int Co_pad) {
    int idx = blockIdx.x * 256 + threadIdx.x;
    if (idx >= Co_pad * 576) return;
    int co = idx / 576, r = idx % 576;
    int kk = r >> 6, ci = r & 63;
    ushort v = 0;
    if (co < Co) v = f2bf(w[(co * 64 + ci) * 9 + kk]);
    wa[idx] = v;
}

// ---------------------------------------------------------------------------
// m97-style implicit-GEMM 3x3 conv (unchanged from round 5).
// ---------------------------------------------------------------------------
template<int NCO, int MODE>
__global__ __launch_bounds__(256, 3) void conv_gemm2_k(
    const ushort* __restrict__ xt, const ushort* __restrict__ wa,
    const float* __restrict__ bias, ushort* __restrict__ y,
    uint* __restrict__ dyxp, ushort* __restrict__ mpl, int Cout) {
    __shared__ ushort Al[NCO * 64 * 64];   // [NCO*64 co][64 ci], row 128 B, swizzled
    __shared__ ushort Bt[64 * 64];         // [64 px][64 ci], row 128 B, swizzled
    int t = threadIdx.x;
    int orig = blockIdx.x;
    int blk = (orig & 7) * 256 + (orig >> 3);   // bijective, 2048 = 8*256; XCD = image
    int b = blk >> 8;
    int h = (blk >> 1) & 127;
    int w0 = (blk & 1) << 6;
    int lane = t & 63;
    int wv = t >> 6;
    int lg = lane >> 4;
    int lr = lane & 15;
    int rs = (lr & 7) << 4;                      // read-side swizzle
    int asw = ((lane & 7) ^ (lane >> 3)) << 4;   // source pre-swizzle for gload_lds
    const char* wab = (const char*)wa;

    f32x4 acc[NCO][4];
#pragma unroll
    for (int n = 0; n < NCO; n++)
#pragma unroll
        for (int j = 0; j < 4; j++) acc[n][j] = f32x4{0, 0, 0, 0};

#pragma unroll 1
    for (int kk = 0; kk < 9; kk++) {
        int ky = kk / 3;
        int kx = kk - ky * 3;
        __syncthreads();
        // ---- stage A: global_load_lds, 1024 B per wave-instr (8 rows) ----
#pragma unroll
        for (int a = 0; a < 2 * NCO; a++) {
            int rb = wv * (NCO * 16) + a * 8;
            const char* g = wab + (size_t)(rb + (lane >> 3)) * 1152 + kk * 128 + asw;
            __builtin_amdgcn_global_load_lds(
                (const __attribute__((address_space(1))) void*)g,
                (__attribute__((address_space(3))) void*)((char*)Al + rb * 128),
                16, 0, 0);
        }
        // ---- stage B: thread -> (px=lane, cg=wv and wv+4), zero at borders ----
        int hy = h + ky - 1;
        int wx = w0 + lane + kx - 1;
        bool val = ((unsigned)hy < 128u) && ((unsigned)wx < 128u);
        uint4 v0 = {0u, 0u, 0u, 0u}, v1 = {0u, 0u, 0u, 0u};
        if (val) {
            const ushort* gb = xt + ((((size_t)b * 8 + wv) << 14) + (hy << 7) + wx) * 8;
            v0 = *(const uint4*)gb;
            v1 = *(const uint4*)(gb + (4ull << 17));   // +4 cg planes
        }
        int swl = (lane & 7) << 4;
        *(uint4*)((char*)Bt + lane * 128 + ((wv * 16) ^ swl)) = v0;
        *(uint4*)((char*)Bt + lane * 128 + (((wv + 4) * 16) ^ swl)) = v1;
        __syncthreads();
        // ---- compute: per wave 32 MFMA, 16 ds_read_b128 ----
#pragma unroll
        for (int n = 0; n < NCO; n++) {
            int ar = n * 64 + wv * 16 + lr;
            bf16x8 a0 = *(const bf16x8*)((char*)Al + ar * 128 + ((lg * 16) ^ rs));
            bf16x8 a1 = *(const bf16x8*)((char*)Al + ar * 128 + ((lg * 16 + 64) ^ rs));
#pragma unroll
            for (int j = 0; j < 4; j++) {
                int pr = j * 16 + lr;
                bf16x8 b0 = *(const bf16x8*)((char*)Bt + pr * 128 + ((lg * 16) ^ rs));
                bf16x8 b1 = *(const bf16x8*)((char*)Bt + pr * 128 + ((lg * 16 + 64) ^ rs));
                acc[n][j] = __builtin_amdgcn_mfma_f32_16x16x32_bf16(a0, b0, acc[n][j], 0, 0, 0);
                acc[n][j] = __builtin_amdgcn_mfma_f32_16x16x32_bf16(a1, b1, acc[n][j], 0, 0, 0);
            }
        }
    }

    // ---- epilogue: D[co][px], co = n*64 + wv*16 + lg*4 + r, px = j*16 + lr ----
#pragma unroll
    for (int n = 0; n < NCO; n++) {
        int co_g = n * 64 + wv * 16 + lg * 4;
        if (co_g < Cout) {
            float bs[4];
#pragma unroll
            for (int r = 0; r < 4; r++) bs[r] = bias[co_g + r];
#pragma unroll
            for (int j = 0; j < 4; j++) {
                int pxl = j * 16 + lr;
                int hw = (h << 7) + w0 + pxl;
                int bhw = (b << 14) + hw;
                if (MODE == 0) {
                    int cg = co_g >> 3, cs = co_g & 7;
                    uint2 s2;
                    s2.x = (uint)f2bf(acc[n][j][0] + bs[0]) | ((uint)f2bf(acc[n][j][1] + bs[1]) << 16);
                    s2.y = (uint)f2bf(acc[n][j][2] + bs[2]) | ((uint)f2bf(acc[n][j][3] + bs[3]) << 16);
                    *(uint2*)(y + ((((size_t)b * 8 + cg) << 14) + hw) * 8 + cs) = s2;
                } else if (co_g < 144) {
                    int p0 = co_g >> 1;
                    uint u0 = (uint)f2bf(acc[n][j][0] + bs[0]) | ((uint)f2bf(acc[n][j][1] + bs[1]) << 16);
                    uint u1 = (uint)f2bf(acc[n][j][2] + bs[2]) | ((uint)f2bf(acc[n][j][3] + bs[3]) << 16);
                    dyxp[(size_t)p0 * BHW + bhw] = u0;
                    dyxp[(size_t)(p0 + 1) * BHW + bhw] = u1;
                } else {
#pragma unroll
                    for (int r = 0; r < 4; r++) {
                        float f = 1.f / (1.f + __expf(-(acc[n][j][r] + bs[r])));
                        mpl[(size_t)(co_g - 144 + r) * BHW + bhw] = f2bf(f);
                    }
                }
            }
        }
    }
}

// ---------------------------------------------------------------------------
// Modulated deformable conv, all-register: each wave owns 16 px x 64 co.
// For MFMA K-step c (K=32), lane's B-fragment = bilinear sample of
// (px = wv*16+lr, dg = (c&1)*4+lg, tap = c>>1) -- 8 group channels = 8 k-elems.
// No LDS, no barriers. A streams from L2-resident wa[64][576].
// ---------------------------------------------------------------------------
__global__ __launch_bounds__(256, 4) void deform_reg_k(
    const ushort* __restrict__ xg, const uint* __restrict__ dyxp,
    const ushort* __restrict__ mpl, const ushort* __restrict__ wa,
    const float* __restrict__ bias, float* __restrict__ out) {
    int t = threadIdx.x;
    int orig = blockIdx.x;
    int blk = (orig & 7) * 256 + (orig >> 3);   // bijective: 2048 = 8 * 256
    int b = blk >> 8;
    int h = (blk >> 1) & 127;
    int w0 = (blk & 1) << 6;
    int lane = t & 63;
    int wv = t >> 6;
    int lg = lane >> 4;
    int lr = lane & 15;
    int wabs = w0 + wv * 16 + lr;               // this lane's pixel column
    int bhw = (b << 14) + (h << 7) + wabs;

    f32x4 acc[4] = {f32x4{0,0,0,0}, f32x4{0,0,0,0}, f32x4{0,0,0,0}, f32x4{0,0,0,0}};

#pragma unroll
    for (int c = 0; c < 18; c++) {
        const int dg_l = ((c & 1) << 2);        // + lg at runtime
        const int tap = c >> 1;
        const int ky = tap / 3;
        const int kx = tap - ky * 3;
        int dg = dg_l + lg;
        int p = dg * 9 + tap;
        uint dyx = dyxp[(size_t)p * BHW + bhw];
        float m = bf2f(mpl[(size_t)p * BHW + bhw]);
        float dy = bf2f((ushort)(dyx & 0xffff));
        float dx = bf2f((ushort)(dyx >> 16));
        float py = dy + (float)(h + ky - 1);
        float px_ = dx + (float)(wabs + kx - 1);
        float fy = floorf(py), fx = floorf(px_);
        int y0 = (int)fy, x0 = (int)fx;
        int y1 = y0 + 1, x1 = x0 + 1;
        float ly = py - fy, lx = px_ - fx;
        bool vy0 = (unsigned)y0 < (unsigned)HH, vy1 = (unsigned)y1 < (unsigned)HH;
        bool vx0 = (unsigned)x0 < (unsigned)WW, vx1 = (unsigned)x1 < (unsigned)WW;
        float w00 = (vy0 && vx0) ? (1.f - ly) * (1.f - lx) * m : 0.f;
        float w01 = (vy0 && vx1) ? (1.f - ly) * lx * m : 0.f;
        float w10 = (vy1 && vx0) ? ly * (1.f - lx) * m : 0.f;
        float w11 = (vy1 && vx1) ? ly * lx * m : 0.f;
        int y0c = min(max(y0, 0), HH - 1), y1c = min(max(y1, 0), HH - 1);
        int x0c = min(max(x0, 0), WW - 1), x1c = min(max(x1, 0), WW - 1);
        const ushort* gb = xg + (((size_t)b * 8 + dg) << 17);
        uint4 q00 = *(const uint4*)(gb + ((y0c << 7) + x0c) * 8);
        uint4 q01 = *(const uint4*)(gb + ((y0c << 7) + x1c) * 8);
        uint4 q10 = *(const uint4*)(gb + ((y1c << 7) + x0c) * 8);
        uint4 q11 = *(const uint4*)(gb + ((y1c << 7) + x1c) * 8);
        const ushort* u00 = (const ushort*)&q00;
        const ushort* u01 = (const ushort*)&q01;
        const ushort* u10 = (const ushort*)&q10;
        const ushort* u11 = (const ushort*)&q11;
        uint pk[4];
#pragma unroll
        for (int c2 = 0; c2 < 4; c2++) {
            float v0 = w00 * bf2f(u00[2*c2])   + w01 * bf2f(u01[2*c2])
                     + w10 * bf2f(u10[2*c2])   + w11 * bf2f(u11[2*c2]);
            float v1 = w00 * bf2f(u00[2*c2+1]) + w01 * bf2f(u01[2*c2+1])
                     + w10 * bf2f(u10[2*c2+1]) + w11 * bf2f(u11[2*c2+1]);
            pk[c2] = (uint)f2bf(v0) | ((uint)f2bf(v1) << 16);
        }
        bf16x8 bfrag = *(bf16x8*)pk;
        const ushort* wac = wa + c * 32 + lg * 8;
#pragma unroll
        for (int n = 0; n < 4; n++) {
            bf16x8 a = *(const bf16x8*)(wac + (size_t)(n * 16 + lr) * 576);
            acc[n] = __builtin_amdgcn_mfma_f32_16x16x32_bf16(a, bfrag, acc[n], 0, 0, 0);
        }
    }

    // ---- epilogue: D[co][px]: co = n*16 + lg*4 + r, px(col) = lr -> wabs ----
    int hw = (h << 7) + wabs;
#pragma unroll
    for (int n = 0; n < 4; n++) {
        int co_g = n * 16 + lg * 4;
#pragma unroll
        for (int r = 0; r < 4; r++) {
            out[((size_t)(b * 64 + co_g + r) << 14) + hw] = acc[n][r] + bias[co_g + r];
        }
    }
}

extern "C" void kernel_launch(void* const* d_in, const int* in_sizes, int n_in,
                              void* d_out, int out_size, void* d_ws, size_t ws_size,
                              hipStream_t stream) {
    const float* cat_fea = (const float*)d_in[0];
    const float* f_fea   = (const float*)d_in[1];
    const float* w_off2d = (const float*)d_in[2];
    const float* b_off2d = (const float*)d_in[3];
    const float* w_coff  = (const float*)d_in[4];
    const float* b_coff  = (const float*)d_in[5];
    const float* w_dconv = (const float*)d_in[6];
    const float* b_dconv = (const float*)d_in[7];
    float* out = (float*)d_out;

    ushort* x1t      = (ushort*)d_ws;              // 8388608 ushorts
    ushort* xft      = x1t + 8388608;              // 8388608
    ushort* off_feat = xft + 8388608;              // 8388608
    uint*   dyxp     = (uint*)(off_feat + 8388608);// 72*131072 uints
    ushort* mpl      = (ushort*)(dyxp + 9437184);  // 72*131072 ushorts
    ushort* wa1      = mpl + 9437184;              // 36864
    ushort* wa2      = wa1 + 36864;                // 147456
    ushort* wad      = wa2 + 147456;               // 36864

    to_gp_bf16<<<2048, 256, 0, stream>>>(cat_fea, x1t);
    to_gp_bf16<<<2048, 256, 0, stream>>>(f_fea, xft);
    prep_wa<<<(64 * 576 + 255) / 256, 256, 0, stream>>>(w_off2d, wa1, 64, 64);
    prep_wa<<<(256 * 576 + 255) / 256, 256, 0, stream>>>(w_coff, wa2, 216, 256);
    prep_wa<<<(64 * 576 + 255) / 256, 256, 0, stream>>>(w_dconv, wad, 64, 64);

    conv_gemm2_k<1, 0><<<2048, 256, 0, stream>>>(x1t, wa1, b_off2d, off_feat,
                                                 nullptr, nullptr, 64);
    conv_gemm2_k<4, 1><<<2048, 256, 0, stream>>>(off_feat, wa2, b_coff, nullptr,
                                                 dyxp, mpl, 216);
    deform_reg_k<<<2048, 256, 0, stream>>>(xft, dyxp, mpl, wad, b_dconv, out);
}

// Round 8
// 187.708 us; speedup vs baseline: 1.0039x; 1.0039x over previous
//
#include <hip/hip_runtime.h>
#include <math.h>

typedef __attribute__((ext_vector_type(4))) float f32x4;
typedef __attribute__((ext_vector_type(8))) short bf16x8;

#define HH 128
#define WW 128
#define HWSZ 16384
#define BHW 131072
#define BB 8

__device__ __forceinline__ float bf2f(ushort u) {
    union { uint i; float f; } x; x.i = ((uint)u) << 16; return x.f;
}
__device__ __forceinline__ ushort f2bf(float f) {
    union { float f; uint i; } x; x.f = f;
    uint r = (x.i + 0x7fffu + ((x.i >> 16) & 1u)) >> 16;
    return (ushort)r;
}

// NCHW fp32 (C=64) -> group-planar bf16 xg[b][cg][hw][8].
__global__ __launch_bounds__(256) void to_gp_bf16(const float* __restrict__ x,
                                                  ushort* __restrict__ y) {
    __shared__ ushort lds[64][66];
    int blk = blockIdx.x;
    int b = blk >> 8;
    int hw0 = (blk & 255) << 6;
    int t = threadIdx.x;
    int lane = t & 63;
    int q = t >> 6;
#pragma unroll
    for (int i = 0; i < 16; i++) {
        int c = i * 4 + q;
        lds[c][lane] = f2bf(x[((size_t)(b * 64 + c) << 14) + hw0 + lane]);
    }
    __syncthreads();
#pragma unroll
    for (int it = 0; it < 2; it++) {
        int id = it * 256 + t;
        int cg = id >> 6;
        int px = id & 63;
        uint pk[4];
#pragma unroll
        for (int j = 0; j < 4; j++)
            pk[j] = (uint)lds[cg * 8 + 2 * j][px] | ((uint)lds[cg * 8 + 2 * j + 1][px] << 16);
        *(uint4*)(y + ((((size_t)b * 8 + cg) << 14) + hw0 + px) * 8) = *(uint4*)pk;
    }
}

// w[Co][64][3][3] fp32 -> wa[Co_pad][576] bf16 with r = kk*64+ci (zero-padded rows).
__global__ __launch_bounds__(256) void prep_wa(const float* __restrict__ w,
                                               ushort* __restrict__ wa, int Co, int Co_pad) {
    int idx = blockIdx.x * 256 + threadIdx.x;
    if (idx >= Co_pad * 576) return;
    int co = idx / 576, r = idx % 576;
    int kk = r >> 6, ci = r & 63;
    ushort v = 0;
    if (co < Co) v = f2bf(w[(co * 64 + ci) * 9 + kk]);
    wa[idx] = v;
}

// ---------------------------------------------------------------------------
// m97-style implicit-GEMM 3x3 conv (unchanged).
// ---------------------------------------------------------------------------
template<int NCO, int MODE>
__global__ __launch_bounds__(256, 3) void conv_gemm2_k(
    const ushort* __restrict__ xt, const ushort* __restrict__ wa,
    const float* __restrict__ bias, ushort* __restrict__ y,
    uint* __restrict__ dyxp, ushort* __restrict__ mpl, int Cout) {
    __shared__ ushort Al[NCO * 64 * 64];   // [NCO*64 co][64 ci], row 128 B, swizzled
    __shared__ ushort Bt[64 * 64];         // [64 px][64 ci], row 128 B, swizzled
    int t = threadIdx.x;
    int orig = blockIdx.x;
    int blk = (orig & 7) * 256 + (orig >> 3);   // bijective, 2048 = 8*256; XCD = image
    int b = blk >> 8;
    int h = (blk >> 1) & 127;
    int w0 = (blk & 1) << 6;
    int lane = t & 63;
    int wv = t >> 6;
    int lg = lane >> 4;
    int lr = lane & 15;
    int rs = (lr & 7) << 4;                      // read-side swizzle
    int asw = ((lane & 7) ^ (lane >> 3)) << 4;   // source pre-swizzle for gload_lds
    const char* wab = (const char*)wa;

    f32x4 acc[NCO][4];
#pragma unroll
    for (int n = 0; n < NCO; n++)
#pragma unroll
        for (int j = 0; j < 4; j++) acc[n][j] = f32x4{0, 0, 0, 0};

#pragma unroll 1
    for (int kk = 0; kk < 9; kk++) {
        int ky = kk / 3;
        int kx = kk - ky * 3;
        __syncthreads();
        // ---- stage A: global_load_lds, 1024 B per wave-instr (8 rows) ----
#pragma unroll
        for (int a = 0; a < 2 * NCO; a++) {
            int rb = wv * (NCO * 16) + a * 8;
            const char* g = wab + (size_t)(rb + (lane >> 3)) * 1152 + kk * 128 + asw;
            __builtin_amdgcn_global_load_lds(
                (const __attribute__((address_space(1))) void*)g,
                (__attribute__((address_space(3))) void*)((char*)Al + rb * 128),
                16, 0, 0);
        }
        // ---- stage B: thread -> (px=lane, cg=wv and wv+4), zero at borders ----
        int hy = h + ky - 1;
        int wx = w0 + lane + kx - 1;
        bool val = ((unsigned)hy < 128u) && ((unsigned)wx < 128u);
        uint4 v0 = {0u, 0u, 0u, 0u}, v1 = {0u, 0u, 0u, 0u};
        if (val) {
            const ushort* gb = xt + ((((size_t)b * 8 + wv) << 14) + (hy << 7) + wx) * 8;
            v0 = *(const uint4*)gb;
            v1 = *(const uint4*)(gb + (4ull << 17));   // +4 cg planes
        }
        int swl = (lane & 7) << 4;
        *(uint4*)((char*)Bt + lane * 128 + ((wv * 16) ^ swl)) = v0;
        *(uint4*)((char*)Bt + lane * 128 + (((wv + 4) * 16) ^ swl)) = v1;
        __syncthreads();
        // ---- compute: per wave 32 MFMA, 16 ds_read_b128 ----
#pragma unroll
        for (int n = 0; n < NCO; n++) {
            int ar = n * 64 + wv * 16 + lr;
            bf16x8 a0 = *(const bf16x8*)((char*)Al + ar * 128 + ((lg * 16) ^ rs));
            bf16x8 a1 = *(const bf16x8*)((char*)Al + ar * 128 + ((lg * 16 + 64) ^ rs));
#pragma unroll
            for (int j = 0; j < 4; j++) {
                int pr = j * 16 + lr;
                bf16x8 b0 = *(const bf16x8*)((char*)Bt + pr * 128 + ((lg * 16) ^ rs));
                bf16x8 b1 = *(const bf16x8*)((char*)Bt + pr * 128 + ((lg * 16 + 64) ^ rs));
                acc[n][j] = __builtin_amdgcn_mfma_f32_16x16x32_bf16(a0, b0, acc[n][j], 0, 0, 0);
                acc[n][j] = __builtin_amdgcn_mfma_f32_16x16x32_bf16(a1, b1, acc[n][j], 0, 0, 0);
            }
        }
    }

    // ---- epilogue: D[co][px], co = n*64 + wv*16 + lg*4 + r, px = j*16 + lr ----
#pragma unroll
    for (int n = 0; n < NCO; n++) {
        int co_g = n * 64 + wv * 16 + lg * 4;
        if (co_g < Cout) {
            float bs[4];
#pragma unroll
            for (int r = 0; r < 4; r++) bs[r] = bias[co_g + r];
#pragma unroll
            for (int j = 0; j < 4; j++) {
                int pxl = j * 16 + lr;
                int hw = (h << 7) + w0 + pxl;
                int bhw = (b << 14) + hw;
                if (MODE == 0) {
                    int cg = co_g >> 3, cs = co_g & 7;
                    uint2 s2;
                    s2.x = (uint)f2bf(acc[n][j][0] + bs[0]) | ((uint)f2bf(acc[n][j][1] + bs[1]) << 16);
                    s2.y = (uint)f2bf(acc[n][j][2] + bs[2]) | ((uint)f2bf(acc[n][j][3] + bs[3]) << 16);
                    *(uint2*)(y + ((((size_t)b * 8 + cg) << 14) + hw) * 8 + cs) = s2;
                } else if (co_g < 144) {
                    int p0 = co_g >> 1;
                    uint u0 = (uint)f2bf(acc[n][j][0] + bs[0]) | ((uint)f2bf(acc[n][j][1] + bs[1]) << 16);
                    uint u1 = (uint)f2bf(acc[n][j][2] + bs[2]) | ((uint)f2bf(acc[n][j][3] + bs[3]) << 16);
                    dyxp[(size_t)p0 * BHW + bhw] = u0;
                    dyxp[(size_t)(p0 + 1) * BHW + bhw] = u1;
                } else {
#pragma unroll
                    for (int r = 0; r < 4; r++) {
                        float f = 1.f / (1.f + __expf(-(acc[n][j][r] + bs[r])));
                        mpl[(size_t)(co_g - 144 + r) * BHW + bhw] = f2bf(f);
                    }
                }
            }
        }
    }
}

// ---------------------------------------------------------------------------
// Modulated deformable conv, all-register with explicit 2-deep pipeline:
// PRE(c+1) issues next step's gathers/A-loads BEFORE BLEND(c)+MFMA(c) consume
// the current stage. Full unroll -> all stage indices static.
// ---------------------------------------------------------------------------
__global__ __launch_bounds__(256, 3) void deform_reg2_k(
    const ushort* __restrict__ xg, const uint* __restrict__ dyxp,
    const ushort* __restrict__ mpl, const ushort* __restrict__ wa,
    const float* __restrict__ bias, float* __restrict__ out) {
    int t = threadIdx.x;
    int orig = blockIdx.x;
    int blk = (orig & 7) * 256 + (orig >> 3);   // bijective: 2048 = 8 * 256
    int b = blk >> 8;
    int h = (blk >> 1) & 127;
    int w0 = (blk & 1) << 6;
    int lane = t & 63;
    int wv = t >> 6;
    int lg = lane >> 4;
    int lr = lane & 15;
    int wabs = w0 + wv * 16 + lr;               // this lane's pixel column
    int bhw = (b << 14) + (h << 7) + wabs;

    // ---- phase 0: all 18 offset words (independent coalesced loads) ----
    uint dyxv[18];
#pragma unroll
    for (int c = 0; c < 18; c++) {
        int dg = ((c & 1) << 2) + lg;
        int tap = c >> 1;
        dyxv[c] = dyxp[(size_t)(dg * 9 + tap) * BHW + bhw];
    }

    uint4 qg[2][4];      // gather stage buffers
    f32x4 wt4[2];        // bilinear weights (mask folded)
    bf16x8 afr[2][4];    // A-fragment stage buffers
    f32x4 acc[4] = {f32x4{0,0,0,0}, f32x4{0,0,0,0}, f32x4{0,0,0,0}, f32x4{0,0,0,0}};

#define DPRE(c) do {                                                            \
    const int tap = (c) >> 1;                                                   \
    const int ky = tap / 3;                                                     \
    const int kx = tap - ky * 3;                                                \
    int dg = (((c) & 1) << 2) + lg;                                             \
    float m = bf2f(mpl[(size_t)(dg * 9 + tap) * BHW + bhw]);                    \
    uint dyx = dyxv[(c)];                                                       \
    float dy = bf2f((ushort)(dyx & 0xffff));                                    \
    float dx = bf2f((ushort)(dyx >> 16));                                       \
    float py = dy + (float)(h + ky - 1);                                        \
    float px_ = dx + (float)(wabs + kx - 1);                                    \
    float fy = floorf(py), fx = floorf(px_);                                    \
    int y0 = (int)fy, x0 = (int)fx;                                             \
    int y1 = y0 + 1, x1 = x0 + 1;                                               \
    float ly = py - fy, lx = px_ - fx;                                          \
    bool vy0 = (unsigned)y0 < 128u, vy1 = (unsigned)y1 < 128u;                  \
    bool vx0 = (unsigned)x0 < 128u, vx1 = (unsigned)x1 < 128u;                  \
    f32x4 wv4;                                                                  \
    wv4[0] = (vy0 && vx0) ? (1.f - ly) * (1.f - lx) * m : 0.f;                  \
    wv4[1] = (vy0 && vx1) ? (1.f - ly) * lx * m : 0.f;                          \
    wv4[2] = (vy1 && vx0) ? ly * (1.f - lx) * m : 0.f;                          \
    wv4[3] = (vy1 && vx1) ? ly * lx * m : 0.f;                                  \
    wt4[(c) & 1] = wv4;                                                         \
    int y0c = min(max(y0, 0), 127), y1c = min(max(y1, 0), 127);                 \
    int x0c = min(max(x0, 0), 127), x1c = min(max(x1, 0), 127);                 \
    const ushort* gb = xg + (((size_t)b * 8 + dg) << 17);                       \
    qg[(c) & 1][0] = *(const uint4*)(gb + ((y0c << 7) + x0c) * 8);              \
    qg[(c) & 1][1] = *(const uint4*)(gb + ((y0c << 7) + x1c) * 8);              \
    qg[(c) & 1][2] = *(const uint4*)(gb + ((y1c << 7) + x0c) * 8);              \
    qg[(c) & 1][3] = *(const uint4*)(gb + ((y1c << 7) + x1c) * 8);              \
} while (0)

#define APRE(c) do {                                                            \
    const ushort* wac = wa + (c) * 32 + lg * 8;                                 \
    _Pragma("unroll")                                                           \
    for (int n = 0; n < 4; n++)                                                 \
        afr[(c) & 1][n] = *(const bf16x8*)(wac + (size_t)(n * 16 + lr) * 576);  \
} while (0)

    DPRE(0);
    APRE(0);

#pragma unroll
    for (int c = 0; c < 18; c++) {
        if (c < 17) {
            DPRE(c + 1);
            APRE(c + 1);
        }
        // ---- BLEND(c): consume stage c&1 ----
        f32x4 wc = wt4[c & 1];
        const ushort* u00 = (const ushort*)&qg[c & 1][0];
        const ushort* u01 = (const ushort*)&qg[c & 1][1];
        const ushort* u10 = (const ushort*)&qg[c & 1][2];
        const ushort* u11 = (const ushort*)&qg[c & 1][3];
        uint pk[4];
#pragma unroll
        for (int c2 = 0; c2 < 4; c2++) {
            float v0 = wc[0] * bf2f(u00[2*c2])   + wc[1] * bf2f(u01[2*c2])
                     + wc[2] * bf2f(u10[2*c2])   + wc[3] * bf2f(u11[2*c2]);
            float v1 = wc[0] * bf2f(u00[2*c2+1]) + wc[1] * bf2f(u01[2*c2+1])
                     + wc[2] * bf2f(u10[2*c2+1]) + wc[3] * bf2f(u11[2*c2+1]);
            pk[c2] = (uint)f2bf(v0) | ((uint)f2bf(v1) << 16);
        }
        bf16x8 bfrag = *(bf16x8*)pk;
#pragma unroll
        for (int n = 0; n < 4; n++)
            acc[n] = __builtin_amdgcn_mfma_f32_16x16x32_bf16(afr[c & 1][n], bfrag, acc[n], 0, 0, 0);
    }
#undef DPRE
#undef APRE

    // ---- epilogue: D[co][px]: co = n*16 + lg*4 + r, px(col) = lr -> wabs ----
    int hw = (h << 7) + wabs;
#pragma unroll
    for (int n = 0; n < 4; n++) {
        int co_g = n * 16 + lg * 4;
#pragma unroll
        for (int r = 0; r < 4; r++) {
            out[((size_t)(b * 64 + co_g + r) << 14) + hw] = acc[n][r] + bias[co_g + r];
        }
    }
}

extern "C" void kernel_launch(void* const* d_in, const int* in_sizes, int n_in,
                              void* d_out, int out_size, void* d_ws, size_t ws_size,
                              hipStream_t stream) {
    const float* cat_fea = (const float*)d_in[0];
    const float* f_fea   = (const float*)d_in[1];
    const float* w_off2d = (const float*)d_in[2];
    const float* b_off2d = (const float*)d_in[3];
    const float* w_coff  = (const float*)d_in[4];
    const float* b_coff  = (const float*)d_in[5];
    const float* w_dconv = (const float*)d_in[6];
    const float* b_dconv = (const float*)d_in[7];
    float* out = (float*)d_out;

    ushort* x1t      = (ushort*)d_ws;              // 8388608 ushorts
    ushort* xft      = x1t + 8388608;              // 8388608
    ushort* off_feat = xft + 8388608;              // 8388608
    uint*   dyxp     = (uint*)(off_feat + 8388608);// 72*131072 uints
    ushort* mpl      = (ushort*)(dyxp + 9437184);  // 72*131072 ushorts
    ushort* wa1      = mpl + 9437184;              // 36864
    ushort* wa2      = wa1 + 36864;                // 147456
    ushort* wad      = wa2 + 147456;               // 36864

    to_gp_bf16<<<2048, 256, 0, stream>>>(cat_fea, x1t);
    to_gp_bf16<<<2048, 256, 0, stream>>>(f_fea, xft);
    prep_wa<<<(64 * 576 + 255) / 256, 256, 0, stream>>>(w_off2d, wa1, 64, 64);
    prep_wa<<<(256 * 576 + 255) / 256, 256, 0, stream>>>(w_coff, wa2, 216, 256);
    prep_wa<<<(64 * 576 + 255) / 256, 256, 0, stream>>>(w_dconv, wad, 64, 64);

    conv_gemm2_k<1, 0><<<2048, 256, 0, stream>>>(x1t, wa1, b_off2d, off_feat,
                                                 nullptr, nullptr, 64);
    conv_gemm2_k<4, 1><<<2048, 256, 0, stream>>>(off_feat, wa2, b_coff, nullptr,
                                                 dyxp, mpl, 216);
    deform_reg2_k<<<2048, 256, 0, stream>>>(xft, dyxp, mpl, wad, b_dconv, out);
}

// Round 9
// 184.904 us; speedup vs baseline: 1.0192x; 1.0152x over previous
//
#include <hip/hip_runtime.h>
#include <math.h>

typedef __attribute__((ext_vector_type(4))) float f32x4;
typedef __attribute__((ext_vector_type(8))) short bf16x8;
typedef __attribute__((ext_vector_type(2))) _Float16 f16x2;
typedef __attribute__((ext_vector_type(8))) _Float16 f16x8;

#define HH 128
#define WW 128
#define HWSZ 16384
#define BHW 131072
#define BB 8

__device__ __forceinline__ float bf2f(ushort u) {
    union { uint i; float f; } x; x.i = ((uint)u) << 16; return x.f;
}
__device__ __forceinline__ ushort f2bf(float f) {
    union { float f; uint i; } x; x.f = f;
    uint r = (x.i + 0x7fffu + ((x.i >> 16) & 1u)) >> 16;
    return (ushort)r;
}
__device__ __forceinline__ ushort f2h_bits(float f) {
    union { _Float16 h; ushort u; } x; x.h = (_Float16)f; return x.u;
}

// NCHW fp32 (C=64) -> group-planar 16-bit xg[b][cg][hw][8]. F16=0: bf16, 1: fp16.
template<int F16>
__global__ __launch_bounds__(256) void to_gp_k(const float* __restrict__ x,
                                               ushort* __restrict__ y) {
    __shared__ ushort lds[64][66];
    int blk = blockIdx.x;
    int b = blk >> 8;
    int hw0 = (blk & 255) << 6;
    int t = threadIdx.x;
    int lane = t & 63;
    int q = t >> 6;
#pragma unroll
    for (int i = 0; i < 16; i++) {
        int c = i * 4 + q;
        float v = x[((size_t)(b * 64 + c) << 14) + hw0 + lane];
        lds[c][lane] = F16 ? f2h_bits(v) : f2bf(v);
    }
    __syncthreads();
#pragma unroll
    for (int it = 0; it < 2; it++) {
        int id = it * 256 + t;
        int cg = id >> 6;
        int px = id & 63;
        uint pk[4];
#pragma unroll
        for (int j = 0; j < 4; j++)
            pk[j] = (uint)lds[cg * 8 + 2 * j][px] | ((uint)lds[cg * 8 + 2 * j + 1][px] << 16);
        *(uint4*)(y + ((((size_t)b * 8 + cg) << 14) + hw0 + px) * 8) = *(uint4*)pk;
    }
}

// w[Co][64][3][3] fp32 -> wa[Co_pad][576] 16-bit with r = kk*64+ci.
template<int F16>
__global__ __launch_bounds__(256) void prep_wa(const float* __restrict__ w,
                                               ushort* __restrict__ wa, int Co, int Co_pad) {
    int idx = blockIdx.x * 256 + threadIdx.x;
    if (idx >= Co_pad * 576) return;
    int co = idx / 576, r = idx % 576;
    int kk = r >> 6, ci = r & 63;
    ushort v = 0;
    if (co < Co) {
        float f = w[(co * 64 + ci) * 9 + kk];
        v = F16 ? f2h_bits(f) : f2bf(f);
    }
    wa[idx] = v;
}

// ---------------------------------------------------------------------------
// m97-style implicit-GEMM 3x3 conv (unchanged).
// ---------------------------------------------------------------------------
template<int NCO, int MODE>
__global__ __launch_bounds__(256, 3) void conv_gemm2_k(
    const ushort* __restrict__ xt, const ushort* __restrict__ wa,
    const float* __restrict__ bias, ushort* __restrict__ y,
    uint* __restrict__ dyxp, ushort* __restrict__ mpl, int Cout) {
    __shared__ ushort Al[NCO * 64 * 64];   // [NCO*64 co][64 ci], row 128 B, swizzled
    __shared__ ushort Bt[64 * 64];         // [64 px][64 ci], row 128 B, swizzled
    int t = threadIdx.x;
    int orig = blockIdx.x;
    int blk = (orig & 7) * 256 + (orig >> 3);   // bijective, 2048 = 8*256; XCD = image
    int b = blk >> 8;
    int h = (blk >> 1) & 127;
    int w0 = (blk & 1) << 6;
    int lane = t & 63;
    int wv = t >> 6;
    int lg = lane >> 4;
    int lr = lane & 15;
    int rs = (lr & 7) << 4;                      // read-side swizzle
    int asw = ((lane & 7) ^ (lane >> 3)) << 4;   // source pre-swizzle for gload_lds
    const char* wab = (const char*)wa;

    f32x4 acc[NCO][4];
#pragma unroll
    for (int n = 0; n < NCO; n++)
#pragma unroll
        for (int j = 0; j < 4; j++) acc[n][j] = f32x4{0, 0, 0, 0};

#pragma unroll 1
    for (int kk = 0; kk < 9; kk++) {
        int ky = kk / 3;
        int kx = kk - ky * 3;
        __syncthreads();
        // ---- stage A: global_load_lds, 1024 B per wave-instr (8 rows) ----
#pragma unroll
        for (int a = 0; a < 2 * NCO; a++) {
            int rb = wv * (NCO * 16) + a * 8;
            const char* g = wab + (size_t)(rb + (lane >> 3)) * 1152 + kk * 128 + asw;
            __builtin_amdgcn_global_load_lds(
                (const __attribute__((address_space(1))) void*)g,
                (__attribute__((address_space(3))) void*)((char*)Al + rb * 128),
                16, 0, 0);
        }
        // ---- stage B: thread -> (px=lane, cg=wv and wv+4), zero at borders ----
        int hy = h + ky - 1;
        int wx = w0 + lane + kx - 1;
        bool val = ((unsigned)hy < 128u) && ((unsigned)wx < 128u);
        uint4 v0 = {0u, 0u, 0u, 0u}, v1 = {0u, 0u, 0u, 0u};
        if (val) {
            const ushort* gb = xt + ((((size_t)b * 8 + wv) << 14) + (hy << 7) + wx) * 8;
            v0 = *(const uint4*)gb;
            v1 = *(const uint4*)(gb + (4ull << 17));   // +4 cg planes
        }
        int swl = (lane & 7) << 4;
        *(uint4*)((char*)Bt + lane * 128 + ((wv * 16) ^ swl)) = v0;
        *(uint4*)((char*)Bt + lane * 128 + (((wv + 4) * 16) ^ swl)) = v1;
        __syncthreads();
        // ---- compute: per wave 32 MFMA, 16 ds_read_b128 ----
#pragma unroll
        for (int n = 0; n < NCO; n++) {
            int ar = n * 64 + wv * 16 + lr;
            bf16x8 a0 = *(const bf16x8*)((char*)Al + ar * 128 + ((lg * 16) ^ rs));
            bf16x8 a1 = *(const bf16x8*)((char*)Al + ar * 128 + ((lg * 16 + 64) ^ rs));
#pragma unroll
            for (int j = 0; j < 4; j++) {
                int pr = j * 16 + lr;
                bf16x8 b0 = *(const bf16x8*)((char*)Bt + pr * 128 + ((lg * 16) ^ rs));
                bf16x8 b1 = *(const bf16x8*)((char*)Bt + pr * 128 + ((lg * 16 + 64) ^ rs));
                acc[n][j] = __builtin_amdgcn_mfma_f32_16x16x32_bf16(a0, b0, acc[n][j], 0, 0, 0);
                acc[n][j] = __builtin_amdgcn_mfma_f32_16x16x32_bf16(a1, b1, acc[n][j], 0, 0, 0);
            }
        }
    }

    // ---- epilogue: D[co][px], co = n*64 + wv*16 + lg*4 + r, px = j*16 + lr ----
#pragma unroll
    for (int n = 0; n < NCO; n++) {
        int co_g = n * 64 + wv * 16 + lg * 4;
        if (co_g < Cout) {
            float bs[4];
#pragma unroll
            for (int r = 0; r < 4; r++) bs[r] = bias[co_g + r];
#pragma unroll
            for (int j = 0; j < 4; j++) {
                int pxl = j * 16 + lr;
                int hw = (h << 7) + w0 + pxl;
                int bhw = (b << 14) + hw;
                if (MODE == 0) {
                    int cg = co_g >> 3, cs = co_g & 7;
                    uint2 s2;
                    s2.x = (uint)f2bf(acc[n][j][0] + bs[0]) | ((uint)f2bf(acc[n][j][1] + bs[1]) << 16);
                    s2.y = (uint)f2bf(acc[n][j][2] + bs[2]) | ((uint)f2bf(acc[n][j][3] + bs[3]) << 16);
                    *(uint2*)(y + ((((size_t)b * 8 + cg) << 14) + hw) * 8 + cs) = s2;
                } else if (co_g < 144) {
                    int p0 = co_g >> 1;
                    uint u0 = (uint)f2bf(acc[n][j][0] + bs[0]) | ((uint)f2bf(acc[n][j][1] + bs[1]) << 16);
                    uint u1 = (uint)f2bf(acc[n][j][2] + bs[2]) | ((uint)f2bf(acc[n][j][3] + bs[3]) << 16);
                    dyxp[(size_t)p0 * BHW + bhw] = u0;
                    dyxp[(size_t)(p0 + 1) * BHW + bhw] = u1;
                } else {
#pragma unroll
                    for (int r = 0; r < 4; r++) {
                        float f = 1.f / (1.f + __expf(-(acc[n][j][r] + bs[r])));
                        mpl[(size_t)(co_g - 144 + r) * BHW + bhw] = f2bf(f);
                    }
                }
            }
        }
    }
}

// ---------------------------------------------------------------------------
// Modulated deformable conv, all-register, fp16 sampling path, pipeline pinned
// with sched_barrier(0): PRE(c+1) gathers are forced to issue before BLEND(c).
// Blend in packed f16 (v_pk_fma_f16); blended regs ARE the f16 MFMA B-fragment.
// ---------------------------------------------------------------------------
__global__ __launch_bounds__(256, 3) void deform_reg3_k(
    const ushort* __restrict__ xg, const uint* __restrict__ dyxp,
    const ushort* __restrict__ mpl, const ushort* __restrict__ wa,
    const float* __restrict__ bias, float* __restrict__ out) {
    int t = threadIdx.x;
    int orig = blockIdx.x;
    int blk = (orig & 7) * 256 + (orig >> 3);   // bijective: 2048 = 8 * 256
    int b = blk >> 8;
    int h = (blk >> 1) & 127;
    int w0 = (blk & 1) << 6;
    int lane = t & 63;
    int wv = t >> 6;
    int lg = lane >> 4;
    int lr = lane & 15;
    int wabs = w0 + wv * 16 + lr;               // this lane's pixel column
    int bhw = (b << 14) + (h << 7) + wabs;

    // ---- phase 0: all offsets + masks (independent coalesced loads) ----
    uint dyxv[18];
    float mv[18];
#pragma unroll
    for (int c = 0; c < 18; c++) {
        int dg = ((c & 1) << 2) + lg;
        int tap = c >> 1;
        dyxv[c] = dyxp[(size_t)(dg * 9 + tap) * BHW + bhw];
        mv[c] = bf2f(mpl[(size_t)(dg * 9 + tap) * BHW + bhw]);
    }

    uint4 qg[2][4];      // gather stage buffers (8 f16 channels x 4 corners)
    f32x4 wt4[2];        // bilinear corner weights (mask folded), fp32
    f16x8 afr[2][4];     // A-fragment stage buffers
    f32x4 acc[4] = {f32x4{0,0,0,0}, f32x4{0,0,0,0}, f32x4{0,0,0,0}, f32x4{0,0,0,0}};

#define DPRE(c) do {                                                            \
    const int tap = (c) >> 1;                                                   \
    const int ky = tap / 3;                                                     \
    const int kx = tap - ky * 3;                                                \
    int dg = (((c) & 1) << 2) + lg;                                             \
    uint dyx = dyxv[(c)];                                                       \
    float dy = bf2f((ushort)(dyx & 0xffff));                                    \
    float dx = bf2f((ushort)(dyx >> 16));                                       \
    float py = dy + (float)(h + ky - 1);                                        \
    float px_ = dx + (float)(wabs + kx - 1);                                    \
    float fy = floorf(py), fx = floorf(px_);                                    \
    int y0 = (int)fy, x0 = (int)fx;                                             \
    int y1 = y0 + 1, x1 = x0 + 1;                                               \
    int y0c = min(max(y0, 0), 127), y1c = min(max(y1, 0), 127);                 \
    int x0c = min(max(x0, 0), 127), x1c = min(max(x1, 0), 127);                 \
    const ushort* gb = xg + (((size_t)b * 8 + dg) << 17);                       \
    qg[(c) & 1][0] = *(const uint4*)(gb + ((y0c << 7) + x0c) * 8);              \
    qg[(c) & 1][1] = *(const uint4*)(gb + ((y0c << 7) + x1c) * 8);              \
    qg[(c) & 1][2] = *(const uint4*)(gb + ((y1c << 7) + x0c) * 8);              \
    qg[(c) & 1][3] = *(const uint4*)(gb + ((y1c << 7) + x1c) * 8);              \
    float ly = py - fy, lx = px_ - fx;                                          \
    bool vy0 = (unsigned)y0 < 128u, vy1 = (unsigned)y1 < 128u;                  \
    bool vx0 = (unsigned)x0 < 128u, vx1 = (unsigned)x1 < 128u;                  \
    float m = mv[(c)];                                                          \
    f32x4 wv4;                                                                  \
    wv4[0] = (vy0 && vx0) ? (1.f - ly) * (1.f - lx) * m : 0.f;                  \
    wv4[1] = (vy0 && vx1) ? (1.f - ly) * lx * m : 0.f;                          \
    wv4[2] = (vy1 && vx0) ? ly * (1.f - lx) * m : 0.f;                          \
    wv4[3] = (vy1 && vx1) ? ly * lx * m : 0.f;                                  \
    wt4[(c) & 1] = wv4;                                                         \
} while (0)

#define APRE(c) do {                                                            \
    const ushort* wac = wa + (c) * 32 + lg * 8;                                 \
    _Pragma("unroll")                                                           \
    for (int n = 0; n < 4; n++)                                                 \
        afr[(c) & 1][n] = *(const f16x8*)(wac + (size_t)(n * 16 + lr) * 576);   \
} while (0)

    DPRE(0);
    APRE(0);

#pragma unroll
    for (int c = 0; c < 18; c++) {
        if (c < 17) {
            DPRE(c + 1);
            APRE(c + 1);
        }
        __builtin_amdgcn_sched_barrier(0);   // pin: c+1 loads issue before BLEND(c)
        // ---- BLEND(c): packed f16, result = B-fragment directly ----
        f32x4 wc = wt4[c & 1];
        _Float16 wh0 = (_Float16)wc[0], wh1 = (_Float16)wc[1];
        _Float16 wh2 = (_Float16)wc[2], wh3 = (_Float16)wc[3];
        f16x2 w0p = {wh0, wh0}, w1p = {wh1, wh1}, w2p = {wh2, wh2}, w3p = {wh3, wh3};
        union { uint4 u4; uint u[4]; } c00, c01, c10, c11;
        c00.u4 = qg[c & 1][0]; c01.u4 = qg[c & 1][1];
        c10.u4 = qg[c & 1][2]; c11.u4 = qg[c & 1][3];
        union { f16x2 p[4]; f16x8 v; } bf;
#pragma unroll
        for (int c2 = 0; c2 < 4; c2++) {
            union { uint u; f16x2 h; } h00, h01, h10, h11;
            h00.u = c00.u[c2]; h01.u = c01.u[c2];
            h10.u = c10.u[c2]; h11.u = c11.u[c2];
            bf.p[c2] = h00.h * w0p + h01.h * w1p + h10.h * w2p + h11.h * w3p;
        }
#pragma unroll
        for (int n = 0; n < 4; n++)
            acc[n] = __builtin_amdgcn_mfma_f32_16x16x32_f16(afr[c & 1][n], bf.v, acc[n], 0, 0, 0);
    }
#undef DPRE
#undef APRE

    // ---- epilogue: D[co][px]: co = n*16 + lg*4 + r, px(col) = lr -> wabs ----
    int hw = (h << 7) + wabs;
#pragma unroll
    for (int n = 0; n < 4; n++) {
        int co_g = n * 16 + lg * 4;
#pragma unroll
        for (int r = 0; r < 4; r++) {
            out[((size_t)(b * 64 + co_g + r) << 14) + hw] = acc[n][r] + bias[co_g + r];
        }
    }
}

extern "C" void kernel_launch(void* const* d_in, const int* in_sizes, int n_in,
                              void* d_out, int out_size, void* d_ws, size_t ws_size,
                              hipStream_t stream) {
    const float* cat_fea = (const float*)d_in[0];
    const float* f_fea   = (const float*)d_in[1];
    const float* w_off2d = (const float*)d_in[2];
    const float* b_off2d = (const float*)d_in[3];
    const float* w_coff  = (const float*)d_in[4];
    const float* b_coff  = (const float*)d_in[5];
    const float* w_dconv = (const float*)d_in[6];
    const float* b_dconv = (const float*)d_in[7];
    float* out = (float*)d_out;

    ushort* x1t      = (ushort*)d_ws;              // 8388608 ushorts (bf16)
    ushort* xft      = x1t + 8388608;              // 8388608 (fp16)
    ushort* off_feat = xft + 8388608;              // 8388608 (bf16)
    uint*   dyxp     = (uint*)(off_feat + 8388608);// 72*131072 uints
    ushort* mpl      = (ushort*)(dyxp + 9437184);  // 72*131072 ushorts
    ushort* wa1      = mpl + 9437184;              // 36864 (bf16)
    ushort* wa2      = wa1 + 36864;                // 147456 (bf16)
    ushort* wad      = wa2 + 147456;               // 36864 (fp16)

    to_gp_k<0><<<2048, 256, 0, stream>>>(cat_fea, x1t);
    to_gp_k<1><<<2048, 256, 0, stream>>>(f_fea, xft);
    prep_wa<0><<<(64 * 576 + 255) / 256, 256, 0, stream>>>(w_off2d, wa1, 64, 64);
    prep_wa<0><<<(256 * 576 + 255) / 256, 256, 0, stream>>>(w_coff, wa2, 216, 256);
    prep_wa<1><<<(64 * 576 + 255) / 256, 256, 0, stream>>>(w_dconv, wad, 64, 64);

    conv_gemm2_k<1, 0><<<2048, 256, 0, stream>>>(x1t, wa1, b_off2d, off_feat,
                                                 nullptr, nullptr, 64);
    conv_gemm2_k<4, 1><<<2048, 256, 0, stream>>>(off_feat, wa2, b_coff, nullptr,
                                                 dyxp, mpl, 216);
    deform_reg3_k<<<2048, 256, 0, stream>>>(xft, dyxp, mpl, wad, b_dconv, out);
}

// Round 10
// 170.304 us; speedup vs baseline: 1.1065x; 1.0857x over previous
//
#include <hip/hip_runtime.h>
#include <math.h>

typedef __attribute__((ext_vector_type(4))) float f32x4;
typedef __attribute__((ext_vector_type(8))) short bf16x8;
typedef __attribute__((ext_vector_type(2))) _Float16 f16x2;
typedef __attribute__((ext_vector_type(8))) _Float16 f16x8;

#define HH 128
#define WW 128
#define HWSZ 16384
#define BHW 131072
#define BB 8

__device__ __forceinline__ float bf2f(ushort u) {
    union { uint i; float f; } x; x.i = ((uint)u) << 16; return x.f;
}
__device__ __forceinline__ ushort f2bf(float f) {
    union { float f; uint i; } x; x.f = f;
    uint r = (x.i + 0x7fffu + ((x.i >> 16) & 1u)) >> 16;
    return (ushort)r;
}
__device__ __forceinline__ ushort f2h_bits(float f) {
    union { _Float16 h; ushort u; } x; x.h = (_Float16)f; return x.u;
}

// NCHW fp32 (C=64) -> group-planar 16-bit xg[b][cg][hw][8]. F16=0: bf16, 1: fp16.
template<int F16>
__global__ __launch_bounds__(256) void to_gp_k(const float* __restrict__ x,
                                               ushort* __restrict__ y) {
    __shared__ ushort lds[64][66];
    int blk = blockIdx.x;
    int b = blk >> 8;
    int hw0 = (blk & 255) << 6;
    int t = threadIdx.x;
    int lane = t & 63;
    int q = t >> 6;
#pragma unroll
    for (int i = 0; i < 16; i++) {
        int c = i * 4 + q;
        float v = x[((size_t)(b * 64 + c) << 14) + hw0 + lane];
        lds[c][lane] = F16 ? f2h_bits(v) : f2bf(v);
    }
    __syncthreads();
#pragma unroll
    for (int it = 0; it < 2; it++) {
        int id = it * 256 + t;
        int cg = id >> 6;
        int px = id & 63;
        uint pk[4];
#pragma unroll
        for (int j = 0; j < 4; j++)
            pk[j] = (uint)lds[cg * 8 + 2 * j][px] | ((uint)lds[cg * 8 + 2 * j + 1][px] << 16);
        *(uint4*)(y + ((((size_t)b * 8 + cg) << 14) + hw0 + px) * 8) = *(uint4*)pk;
    }
}

// w[Co][64][3][3] fp32 -> wa[Co_pad][576] 16-bit with r = kk*64+ci.
template<int F16>
__global__ __launch_bounds__(256) void prep_wa(const float* __restrict__ w,
                                               ushort* __restrict__ wa, int Co, int Co_pad) {
    int idx = blockIdx.x * 256 + threadIdx.x;
    if (idx >= Co_pad * 576) return;
    int co = idx / 576, r = idx % 576;
    int kk = r >> 6, ci = r & 63;
    ushort v = 0;
    if (co < Co) {
        float f = w[(co * 64 + ci) * 9 + kk];
        v = F16 ? f2h_bits(f) : f2bf(f);
    }
    wa[idx] = v;
}

// ---------------------------------------------------------------------------
// m97-style implicit-GEMM 3x3 conv (unchanged).
// ---------------------------------------------------------------------------
template<int NCO, int MODE>
__global__ __launch_bounds__(256, 3) void conv_gemm2_k(
    const ushort* __restrict__ xt, const ushort* __restrict__ wa,
    const float* __restrict__ bias, ushort* __restrict__ y,
    uint* __restrict__ dyxp, ushort* __restrict__ mpl, int Cout) {
    __shared__ ushort Al[NCO * 64 * 64];   // [NCO*64 co][64 ci], row 128 B, swizzled
    __shared__ ushort Bt[64 * 64];         // [64 px][64 ci], row 128 B, swizzled
    int t = threadIdx.x;
    int orig = blockIdx.x;
    int blk = (orig & 7) * 256 + (orig >> 3);   // bijective, 2048 = 8*256; XCD = image
    int b = blk >> 8;
    int h = (blk >> 1) & 127;
    int w0 = (blk & 1) << 6;
    int lane = t & 63;
    int wv = t >> 6;
    int lg = lane >> 4;
    int lr = lane & 15;
    int rs = (lr & 7) << 4;                      // read-side swizzle
    int asw = ((lane & 7) ^ (lane >> 3)) << 4;   // source pre-swizzle for gload_lds
    const char* wab = (const char*)wa;

    f32x4 acc[NCO][4];
#pragma unroll
    for (int n = 0; n < NCO; n++)
#pragma unroll
        for (int j = 0; j < 4; j++) acc[n][j] = f32x4{0, 0, 0, 0};

#pragma unroll 1
    for (int kk = 0; kk < 9; kk++) {
        int ky = kk / 3;
        int kx = kk - ky * 3;
        __syncthreads();
        // ---- stage A: global_load_lds, 1024 B per wave-instr (8 rows) ----
#pragma unroll
        for (int a = 0; a < 2 * NCO; a++) {
            int rb = wv * (NCO * 16) + a * 8;
            const char* g = wab + (size_t)(rb + (lane >> 3)) * 1152 + kk * 128 + asw;
            __builtin_amdgcn_global_load_lds(
                (const __attribute__((address_space(1))) void*)g,
                (__attribute__((address_space(3))) void*)((char*)Al + rb * 128),
                16, 0, 0);
        }
        // ---- stage B: thread -> (px=lane, cg=wv and wv+4), zero at borders ----
        int hy = h + ky - 1;
        int wx = w0 + lane + kx - 1;
        bool val = ((unsigned)hy < 128u) && ((unsigned)wx < 128u);
        uint4 v0 = {0u, 0u, 0u, 0u}, v1 = {0u, 0u, 0u, 0u};
        if (val) {
            const ushort* gb = xt + ((((size_t)b * 8 + wv) << 14) + (hy << 7) + wx) * 8;
            v0 = *(const uint4*)gb;
            v1 = *(const uint4*)(gb + (4ull << 17));   // +4 cg planes
        }
        int swl = (lane & 7) << 4;
        *(uint4*)((char*)Bt + lane * 128 + ((wv * 16) ^ swl)) = v0;
        *(uint4*)((char*)Bt + lane * 128 + (((wv + 4) * 16) ^ swl)) = v1;
        __syncthreads();
        // ---- compute: per wave 32 MFMA, 16 ds_read_b128 ----
#pragma unroll
        for (int n = 0; n < NCO; n++) {
            int ar = n * 64 + wv * 16 + lr;
            bf16x8 a0 = *(const bf16x8*)((char*)Al + ar * 128 + ((lg * 16) ^ rs));
            bf16x8 a1 = *(const bf16x8*)((char*)Al + ar * 128 + ((lg * 16 + 64) ^ rs));
#pragma unroll
            for (int j = 0; j < 4; j++) {
                int pr = j * 16 + lr;
                bf16x8 b0 = *(const bf16x8*)((char*)Bt + pr * 128 + ((lg * 16) ^ rs));
                bf16x8 b1 = *(const bf16x8*)((char*)Bt + pr * 128 + ((lg * 16 + 64) ^ rs));
                acc[n][j] = __builtin_amdgcn_mfma_f32_16x16x32_bf16(a0, b0, acc[n][j], 0, 0, 0);
                acc[n][j] = __builtin_amdgcn_mfma_f32_16x16x32_bf16(a1, b1, acc[n][j], 0, 0, 0);
            }
        }
    }

    // ---- epilogue: D[co][px], co = n*64 + wv*16 + lg*4 + r, px = j*16 + lr ----
#pragma unroll
    for (int n = 0; n < NCO; n++) {
        int co_g = n * 64 + wv * 16 + lg * 4;
        if (co_g < Cout) {
            float bs[4];
#pragma unroll
            for (int r = 0; r < 4; r++) bs[r] = bias[co_g + r];
#pragma unroll
            for (int j = 0; j < 4; j++) {
                int pxl = j * 16 + lr;
                int hw = (h << 7) + w0 + pxl;
                int bhw = (b << 14) + hw;
                if (MODE == 0) {
                    int cg = co_g >> 3, cs = co_g & 7;
                    uint2 s2;
                    s2.x = (uint)f2bf(acc[n][j][0] + bs[0]) | ((uint)f2bf(acc[n][j][1] + bs[1]) << 16);
                    s2.y = (uint)f2bf(acc[n][j][2] + bs[2]) | ((uint)f2bf(acc[n][j][3] + bs[3]) << 16);
                    *(uint2*)(y + ((((size_t)b * 8 + cg) << 14) + hw) * 8 + cs) = s2;
                } else if (co_g < 144) {
                    int p0 = co_g >> 1;
                    uint u0 = (uint)f2bf(acc[n][j][0] + bs[0]) | ((uint)f2bf(acc[n][j][1] + bs[1]) << 16);
                    uint u1 = (uint)f2bf(acc[n][j][2] + bs[2]) | ((uint)f2bf(acc[n][j][3] + bs[3]) << 16);
                    dyxp[(size_t)p0 * BHW + bhw] = u0;
                    dyxp[(size_t)(p0 + 1) * BHW + bhw] = u1;
                } else {
#pragma unroll
                    for (int r = 0; r < 4; r++) {
                        float f = 1.f / (1.f + __expf(-(acc[n][j][r] + bs[r])));
                        mpl[(size_t)(co_g - 144 + r) * BHW + bhw] = f2bf(f);
                    }
                }
            }
        }
    }
}

// ---------------------------------------------------------------------------
// Deform sampling kernel: one thread per (plane p = dg*9+tap, bhw).
// Pure TLP, no pipeline needed. Writes vt[p][bhw][8ch] bf16, coalesced 16B.
// Grid (512, 72); bx swizzled so XCD k owns image k (xg image L2-resident).
// ---------------------------------------------------------------------------
__global__ __launch_bounds__(256) void sample_k(
    const ushort* __restrict__ xg, const uint* __restrict__ dyxp,
    const ushort* __restrict__ mpl, ushort* __restrict__ vt) {
    int p = blockIdx.y;              // 0..71
    int dg = p / 9, tap = p - dg * 9;
    int ky = tap / 3, kx = tap - ky * 3;
    int bx = blockIdx.x;             // 0..511
    int bxs = (bx & 7) * 64 + (bx >> 3);   // XCD k -> image k
    int bhw = (bxs << 8) + threadIdx.x;
    int b = bhw >> 14;
    int h = (bhw >> 7) & 127;
    int w = bhw & 127;

    uint dyx = dyxp[(size_t)p * BHW + bhw];
    float m = bf2f(mpl[(size_t)p * BHW + bhw]);
    float dy = bf2f((ushort)(dyx & 0xffff));
    float dx = bf2f((ushort)(dyx >> 16));
    float py = dy + (float)(h + ky - 1);
    float px_ = dx + (float)(w + kx - 1);
    float fy = floorf(py), fx = floorf(px_);
    int y0 = (int)fy, x0 = (int)fx;
    int y1 = y0 + 1, x1 = x0 + 1;
    float ly = py - fy, lx = px_ - fx;
    bool vy0 = (unsigned)y0 < 128u, vy1 = (unsigned)y1 < 128u;
    bool vx0 = (unsigned)x0 < 128u, vx1 = (unsigned)x1 < 128u;
    float w00 = (vy0 && vx0) ? (1.f - ly) * (1.f - lx) * m : 0.f;
    float w01 = (vy0 && vx1) ? (1.f - ly) * lx * m : 0.f;
    float w10 = (vy1 && vx0) ? ly * (1.f - lx) * m : 0.f;
    float w11 = (vy1 && vx1) ? ly * lx * m : 0.f;
    int y0c = min(max(y0, 0), 127), y1c = min(max(y1, 0), 127);
    int x0c = min(max(x0, 0), 127), x1c = min(max(x1, 0), 127);
    const ushort* gb = xg + (((size_t)b * 8 + dg) << 17);
    uint4 q00 = *(const uint4*)(gb + ((y0c << 7) + x0c) * 8);
    uint4 q01 = *(const uint4*)(gb + ((y0c << 7) + x1c) * 8);
    uint4 q10 = *(const uint4*)(gb + ((y1c << 7) + x0c) * 8);
    uint4 q11 = *(const uint4*)(gb + ((y1c << 7) + x1c) * 8);
    const ushort* u00 = (const ushort*)&q00;
    const ushort* u01 = (const ushort*)&q01;
    const ushort* u10 = (const ushort*)&q10;
    const ushort* u11 = (const ushort*)&q11;
    uint pk[4];
#pragma unroll
    for (int c2 = 0; c2 < 4; c2++) {
        float v0 = w00 * bf2f(u00[2*c2])   + w01 * bf2f(u01[2*c2])
                 + w10 * bf2f(u10[2*c2])   + w11 * bf2f(u11[2*c2]);
        float v1 = w00 * bf2f(u00[2*c2+1]) + w01 * bf2f(u01[2*c2+1])
                 + w10 * bf2f(u10[2*c2+1]) + w11 * bf2f(u11[2*c2+1]);
        pk[c2] = (uint)f2bf(v0) | ((uint)f2bf(v1) << 16);
    }
    *(uint4*)(vt + ((size_t)p * BHW + bhw) * 8) = *(uint4*)pk;
}

// ---------------------------------------------------------------------------
// Deform GEMM: conv_gemm2 structure, B sourced from materialized vt planes
// (coalesced, no borders). 64co x 64px x K=576. Output NCHW fp32 + bias.
// ---------------------------------------------------------------------------
__global__ __launch_bounds__(256, 3) void dgemm_k(
    const ushort* __restrict__ vt, const ushort* __restrict__ wa,
    const float* __restrict__ bias, float* __restrict__ out) {
    __shared__ ushort Al[64 * 64];
    __shared__ ushort Bt[64 * 64];
    int t = threadIdx.x;
    int orig = blockIdx.x;
    int blk = (orig & 7) * 256 + (orig >> 3);   // XCD = image
    int b = blk >> 8;
    int h = (blk >> 1) & 127;
    int w0 = (blk & 1) << 6;
    int lane = t & 63;
    int wv = t >> 6;
    int lg = lane >> 4;
    int lr = lane & 15;
    int rs = (lr & 7) << 4;
    int asw = ((lane & 7) ^ (lane >> 3)) << 4;
    const char* wab = (const char*)wa;
    int bhw0 = (b << 14) + (h << 7) + w0;

    f32x4 acc[4] = {f32x4{0,0,0,0}, f32x4{0,0,0,0}, f32x4{0,0,0,0}, f32x4{0,0,0,0}};

#pragma unroll 1
    for (int kk = 0; kk < 9; kk++) {
        __syncthreads();
        // ---- stage A: weights via global_load_lds ----
#pragma unroll
        for (int a = 0; a < 2; a++) {
            int rb = wv * 16 + a * 8;
            const char* g = wab + (size_t)(rb + (lane >> 3)) * 1152 + kk * 128 + asw;
            __builtin_amdgcn_global_load_lds(
                (const __attribute__((address_space(1))) void*)g,
                (__attribute__((address_space(3))) void*)((char*)Al + rb * 128),
                16, 0, 0);
        }
        // ---- stage B: vt planes dg=wv and wv+4 of tap kk, coalesced ----
        uint4 v0 = *(const uint4*)(vt + ((size_t)(wv * 9 + kk) * BHW + bhw0 + lane) * 8);
        uint4 v1 = *(const uint4*)(vt + ((size_t)((wv + 4) * 9 + kk) * BHW + bhw0 + lane) * 8);
        int swl = (lane & 7) << 4;
        *(uint4*)((char*)Bt + lane * 128 + ((wv * 16) ^ swl)) = v0;
        *(uint4*)((char*)Bt + lane * 128 + (((wv + 4) * 16) ^ swl)) = v1;
        __syncthreads();
        // ---- compute ----
        int ar = wv * 16 + lr;
        bf16x8 a0 = *(const bf16x8*)((char*)Al + ar * 128 + ((lg * 16) ^ rs));
        bf16x8 a1 = *(const bf16x8*)((char*)Al + ar * 128 + ((lg * 16 + 64) ^ rs));
#pragma unroll
        for (int j = 0; j < 4; j++) {
            int pr = j * 16 + lr;
            bf16x8 b0 = *(const bf16x8*)((char*)Bt + pr * 128 + ((lg * 16) ^ rs));
            bf16x8 b1 = *(const bf16x8*)((char*)Bt + pr * 128 + ((lg * 16 + 64) ^ rs));
            acc[j] = __builtin_amdgcn_mfma_f32_16x16x32_bf16(a0, b0, acc[j], 0, 0, 0);
            acc[j] = __builtin_amdgcn_mfma_f32_16x16x32_bf16(a1, b1, acc[j], 0, 0, 0);
        }
    }

    // ---- epilogue: out NCHW fp32. co = wv*16+lg*4+r, px = j*16+lr ----
    int co_g = wv * 16 + lg * 4;
    float bs[4];
#pragma unroll
    for (int r = 0; r < 4; r++) bs[r] = bias[co_g + r];
#pragma unroll
    for (int j = 0; j < 4; j++) {
        int hw = (h << 7) + w0 + j * 16 + lr;
#pragma unroll
        for (int r = 0; r < 4; r++) {
            out[((size_t)(b * 64 + co_g + r) << 14) + hw] = acc[j][r] + bs[r];
        }
    }
}

// ---------------------------------------------------------------------------
// Fallback (ws too small): round-9 all-register deform, fp16 path.
// ---------------------------------------------------------------------------
__global__ __launch_bounds__(256, 3) void deform_reg3_k(
    const ushort* __restrict__ xg, const uint* __restrict__ dyxp,
    const ushort* __restrict__ mpl, const ushort* __restrict__ wa,
    const float* __restrict__ bias, float* __restrict__ out) {
    int t = threadIdx.x;
    int orig = blockIdx.x;
    int blk = (orig & 7) * 256 + (orig >> 3);
    int b = blk >> 8;
    int h = (blk >> 1) & 127;
    int w0 = (blk & 1) << 6;
    int lane = t & 63;
    int wv = t >> 6;
    int lg = lane >> 4;
    int lr = lane & 15;
    int wabs = w0 + wv * 16 + lr;
    int bhw = (b << 14) + (h << 7) + wabs;

    uint dyxv[18];
    float mv[18];
#pragma unroll
    for (int c = 0; c < 18; c++) {
        int dg = ((c & 1) << 2) + lg;
        int tap = c >> 1;
        dyxv[c] = dyxp[(size_t)(dg * 9 + tap) * BHW + bhw];
        mv[c] = bf2f(mpl[(size_t)(dg * 9 + tap) * BHW + bhw]);
    }

    uint4 qg[2][4];
    f32x4 wt4[2];
    f16x8 afr[2][4];
    f32x4 acc[4] = {f32x4{0,0,0,0}, f32x4{0,0,0,0}, f32x4{0,0,0,0}, f32x4{0,0,0,0}};

#define DPRE(c) do {                                                            \
    const int tap = (c) >> 1;                                                   \
    const int ky = tap / 3;                                                     \
    const int kx = tap - ky * 3;                                                \
    int dg = (((c) & 1) << 2) + lg;                                             \
    uint dyx = dyxv[(c)];                                                       \
    float dy = bf2f((ushort)(dyx & 0xffff));                                    \
    float dx = bf2f((ushort)(dyx >> 16));                                       \
    float py = dy + (float)(h + ky - 1);                                        \
    float px_ = dx + (float)(wabs + kx - 1);                                    \
    float fy = floorf(py), fx = floorf(px_);                                    \
    int y0 = (int)fy, x0 = (int)fx;                                             \
    int y1 = y0 + 1, x1 = x0 + 1;                                               \
    int y0c = min(max(y0, 0), 127), y1c = min(max(y1, 0), 127);                 \
    int x0c = min(max(x0, 0), 127), x1c = min(max(x1, 0), 127);                 \
    const ushort* gb = xg + (((size_t)b * 8 + dg) << 17);                       \
    qg[(c) & 1][0] = *(const uint4*)(gb + ((y0c << 7) + x0c) * 8);              \
    qg[(c) & 1][1] = *(const uint4*)(gb + ((y0c << 7) + x1c) * 8);              \
    qg[(c) & 1][2] = *(const uint4*)(gb + ((y1c << 7) + x0c) * 8);              \
    qg[(c) & 1][3] = *(const uint4*)(gb + ((y1c << 7) + x1c) * 8);              \
    float ly = py - fy, lx = px_ - fx;                                          \
    bool vy0 = (unsigned)y0 < 128u, vy1 = (unsigned)y1 < 128u;                  \
    bool vx0 = (unsigned)x0 < 128u, vx1 = (unsigned)x1 < 128u;                  \
    float m = mv[(c)];                                                          \
    f32x4 wv4;                                                                  \
    wv4[0] = (vy0 && vx0) ? (1.f - ly) * (1.f - lx) * m : 0.f;                  \
    wv4[1] = (vy0 && vx1) ? (1.f - ly) * lx * m : 0.f;                          \
    wv4[2] = (vy1 && vx0) ? ly * (1.f - lx) * m : 0.f;                          \
    wv4[3] = (vy1 && vx1) ? ly * lx * m : 0.f;                                  \
    wt4[(c) & 1] = wv4;                                                         \
} while (0)

#define APRE(c) do {                                                            \
    const ushort* wac = wa + (c) * 32 + lg * 8;                                 \
    _Pragma("unroll")                                                           \
    for (int n = 0; n < 4; n++)                                                 \
        afr[(c) & 1][n] = *(const f16x8*)(wac + (size_t)(n * 16 + lr) * 576);   \
} while (0)

    DPRE(0);
    APRE(0);

#pragma unroll
    for (int c = 0; c < 18; c++) {
        if (c < 17) {
            DPRE(c + 1);
            APRE(c + 1);
        }
        __builtin_amdgcn_sched_barrier(0);
        f32x4 wc = wt4[c & 1];
        _Float16 wh0 = (_Float16)wc[0], wh1 = (_Float16)wc[1];
        _Float16 wh2 = (_Float16)wc[2], wh3 = (_Float16)wc[3];
        f16x2 w0p = {wh0, wh0}, w1p = {wh1, wh1}, w2p = {wh2, wh2}, w3p = {wh3, wh3};
        union { uint4 u4; uint u[4]; } c00, c01, c10, c11;
        c00.u4 = qg[c & 1][0]; c01.u4 = qg[c & 1][1];
        c10.u4 = qg[c & 1][2]; c11.u4 = qg[c & 1][3];
        union { f16x2 p[4]; f16x8 v; } bf;
#pragma unroll
        for (int c2 = 0; c2 < 4; c2++) {
            union { uint u; f16x2 h; } h00, h01, h10, h11;
            h00.u = c00.u[c2]; h01.u = c01.u[c2];
            h10.u = c10.u[c2]; h11.u = c11.u[c2];
            bf.p[c2] = h00.h * w0p + h01.h * w1p + h10.h * w2p + h11.h * w3p;
        }
#pragma unroll
        for (int n = 0; n < 4; n++)
            acc[n] = __builtin_amdgcn_mfma_f32_16x16x32_f16(afr[c & 1][n], bf.v, acc[n], 0, 0, 0);
    }
#undef DPRE
#undef APRE

    int hw = (h << 7) + wabs;
#pragma unroll
    for (int n = 0; n < 4; n++) {
        int co_g = n * 16 + lg * 4;
#pragma unroll
        for (int r = 0; r < 4; r++) {
            out[((size_t)(b * 64 + co_g + r) << 14) + hw] = acc[n][r] + bias[co_g + r];
        }
    }
}

extern "C" void kernel_launch(void* const* d_in, const int* in_sizes, int n_in,
                              void* d_out, int out_size, void* d_ws, size_t ws_size,
                              hipStream_t stream) {
    const float* cat_fea = (const float*)d_in[0];
    const float* f_fea   = (const float*)d_in[1];
    const float* w_off2d = (const float*)d_in[2];
    const float* b_off2d = (const float*)d_in[3];
    const float* w_coff  = (const float*)d_in[4];
    const float* b_coff  = (const float*)d_in[5];
    const float* w_dconv = (const float*)d_in[6];
    const float* b_dconv = (const float*)d_in[7];
    float* out = (float*)d_out;

    const size_t NEED_SG = 224837632ull;   // bytes for the sample+gemm path

    if (ws_size >= NEED_SG) {
        // ---- sample+gemm path ----
        ushort* xft  = (ushort*)d_ws;            // 8388608 ush (bf16)
        uint*   dyxp = (uint*)(xft + 8388608);   // 9437184 uints
        ushort* mpl  = (ushort*)(dyxp + 9437184);// 9437184 ush
        ushort* wa1  = mpl + 9437184;            // 36864
        ushort* wa2  = wa1 + 36864;              // 147456
        ushort* wad  = wa2 + 147456;             // 36864 (bf16)
        ushort* vt   = wad + 36864;              // 75497472 ush = 151 MB
        ushort* x1t      = vt;                   // aliased: dead before sample_k
        ushort* off_feat = vt + 8388608;         // aliased: dead before sample_k

        to_gp_k<0><<<2048, 256, 0, stream>>>(cat_fea, x1t);
        to_gp_k<0><<<2048, 256, 0, stream>>>(f_fea, xft);
        prep_wa<0><<<(64 * 576 + 255) / 256, 256, 0, stream>>>(w_off2d, wa1, 64, 64);
        prep_wa<0><<<(256 * 576 + 255) / 256, 256, 0, stream>>>(w_coff, wa2, 216, 256);
        prep_wa<0><<<(64 * 576 + 255) / 256, 256, 0, stream>>>(w_dconv, wad, 64, 64);

        conv_gemm2_k<1, 0><<<2048, 256, 0, stream>>>(x1t, wa1, b_off2d, off_feat,
                                                     nullptr, nullptr, 64);
        conv_gemm2_k<4, 1><<<2048, 256, 0, stream>>>(off_feat, wa2, b_coff, nullptr,
                                                     dyxp, mpl, 216);
        sample_k<<<dim3(512, 72), 256, 0, stream>>>(xft, dyxp, mpl, vt);
        dgemm_k<<<2048, 256, 0, stream>>>(vt, wad, b_dconv, out);
    } else {
        // ---- fallback: round-9 layout + all-register deform ----
        ushort* x1t      = (ushort*)d_ws;
        ushort* xft      = x1t + 8388608;              // fp16
        ushort* off_feat = xft + 8388608;
        uint*   dyxp     = (uint*)(off_feat + 8388608);
        ushort* mpl      = (ushort*)(dyxp + 9437184);
        ushort* wa1      = mpl + 9437184;
        ushort* wa2      = wa1 + 36864;
        ushort* wad      = wa2 + 147456;               // fp16

        to_gp_k<0><<<2048, 256, 0, stream>>>(cat_fea, x1t);
        to_gp_k<1><<<2048, 256, 0, stream>>>(f_fea, xft);
        prep_wa<0><<<(64 * 576 + 255) / 256, 256, 0, stream>>>(w_off2d, wa1, 64, 64);
        prep_wa<0><<<(256 * 576 + 255) / 256, 256, 0, stream>>>(w_coff, wa2, 216, 256);
        prep_wa<1><<<(64 * 576 + 255) / 256, 256, 0, stream>>>(w_dconv, wad, 64, 64);

        conv_gemm2_k<1, 0><<<2048, 256, 0, stream>>>(x1t, wa1, b_off2d, off_feat,
                                                     nullptr, nullptr, 64);
        conv_gemm2_k<4, 1><<<2048, 256, 0, stream>>>(off_feat, wa2, b_coff, nullptr,
                                                     dyxp, mpl, 216);
        deform_reg3_k<<<2048, 256, 0, stream>>>(xft, dyxp, mpl, wad, b_dconv, out);
    }
}